// Round 1
// baseline (59.531 us; speedup 1.0000x reference)
//
#include <hip/hip_runtime.h>

#define BATCH 64
#define NADJ  512
#define F     128
#define CROP0 128
#define CROP1 384
#define CN    256   // crop size
#define BN_EPS 1e-5f

// ---------------------------------------------------------------------------
// K1: S[b, ml, f] = sum_i input[b, CROP0+ml, i] * W[i, f]   (ml in [0,256))
// Tiled GEMM: 32 m-rows x 128 f per block, K staged in 64-chunks.
// ---------------------------------------------------------------------------
__global__ __launch_bounds__(256) void support_kernel(
    const float* __restrict__ input, const float* __restrict__ W,
    float* __restrict__ S) {
  const int b  = blockIdx.y;
  const int m0 = blockIdx.x * 32;
  __shared__ float w_lds[64][128];   // w_lds[ii][f]
  __shared__ float at_lds[64][36];   // at_lds[ii][ml], padded (36) vs bank conflicts
  const int tid = threadIdx.x;
  const int f0  = (tid & 31) * 4;
  const int ml0 = (tid >> 5) * 4;
  float acc[4][4] = {};

  for (int ic = 0; ic < 128; ic += 64) {
    __syncthreads();
    // stage W chunk: 64 x 128, coalesced
    for (int idx = tid; idx < 64 * 128; idx += 256) {
      int ii = idx >> 7, f = idx & 127;
      w_lds[ii][f] = W[(size_t)(ic + ii) * F + f];
    }
    // stage input chunk transposed: at[ii][ml] = input[b][CROP0+m0+ml][ic+ii]
    for (int idx = tid; idx < 32 * 64; idx += 256) {
      int ml = idx >> 6, ii = idx & 63;
      at_lds[ii][ml] =
          input[((size_t)b * NADJ + CROP0 + m0 + ml) * F + ic + ii];
    }
    __syncthreads();
#pragma unroll 4
    for (int ii = 0; ii < 64; ++ii) {
      float4 wv = *reinterpret_cast<const float4*>(&w_lds[ii][f0]);
      float4 av = *reinterpret_cast<const float4*>(&at_lds[ii][ml0]);
      const float wa[4] = {wv.x, wv.y, wv.z, wv.w};
      const float aa[4] = {av.x, av.y, av.z, av.w};
#pragma unroll
      for (int r = 0; r < 4; ++r)
#pragma unroll
        for (int j = 0; j < 4; ++j)
          acc[r][j] = fmaf(aa[r], wa[j], acc[r][j]);
    }
  }
#pragma unroll
  for (int r = 0; r < 4; ++r) {
    float4 v = make_float4(acc[r][0], acc[r][1], acc[r][2], acc[r][3]);
    *reinterpret_cast<float4*>(
        &S[((size_t)b * CN + m0 + ml0 + r) * F + f0]) = v;
  }
}

// ---------------------------------------------------------------------------
// K2: O[b, CROP0+nl, f] = sum_mm adj[b, CROP0+nl, CROP0+mm] * S[b, mm, f]
// Tiled GEMM: 32 n-rows x 128 f per block, m staged in 64-chunks.
// Writes into d_out crop rows (reused as staging for the BN pass).
// ---------------------------------------------------------------------------
__global__ __launch_bounds__(256) void aggregate_kernel(
    const float* __restrict__ adj, const float* __restrict__ S,
    float* __restrict__ out) {
  const int b  = blockIdx.y;
  const int n0 = blockIdx.x * 32;
  __shared__ float s_lds[64][128];   // s_lds[mm][f]
  __shared__ float at_lds[64][36];   // at_lds[mm][nl], padded
  const int tid = threadIdx.x;
  const int f0  = (tid & 31) * 4;
  const int nl0 = (tid >> 5) * 4;
  float acc[4][4] = {};

  const float* adjb = adj + (size_t)b * NADJ * NADJ;
  const float* Sb   = S + (size_t)b * CN * F;

  for (int mc = 0; mc < CN; mc += 64) {
    __syncthreads();
    for (int idx = tid; idx < 64 * 128; idx += 256) {
      int mm = idx >> 7, f = idx & 127;
      s_lds[mm][f] = Sb[(size_t)(mc + mm) * F + f];
    }
    for (int idx = tid; idx < 32 * 64; idx += 256) {
      int nl = idx >> 6, mm = idx & 63;
      at_lds[mm][nl] =
          adjb[(size_t)(CROP0 + n0 + nl) * NADJ + CROP0 + mc + mm];
    }
    __syncthreads();
#pragma unroll 4
    for (int mm = 0; mm < 64; ++mm) {
      float4 sv = *reinterpret_cast<const float4*>(&s_lds[mm][f0]);
      float4 av = *reinterpret_cast<const float4*>(&at_lds[mm][nl0]);
      const float sa[4] = {sv.x, sv.y, sv.z, sv.w};
      const float aa[4] = {av.x, av.y, av.z, av.w};
#pragma unroll
      for (int r = 0; r < 4; ++r)
#pragma unroll
        for (int j = 0; j < 4; ++j)
          acc[r][j] = fmaf(aa[r], sa[j], acc[r][j]);
    }
  }
#pragma unroll
  for (int r = 0; r < 4; ++r) {
    float4 v = make_float4(acc[r][0], acc[r][1], acc[r][2], acc[r][3]);
    *reinterpret_cast<float4*>(
        &out[((size_t)b * NADJ + CROP0 + n0 + nl0 + r) * F + f0]) = v;
  }
}

// ---------------------------------------------------------------------------
// K3: per-feature batch stats over B=64 for crop features (nl,f).
// stats[0:32768) = mean, stats[32768:65536) = rsqrt(var+eps)
// ---------------------------------------------------------------------------
__global__ __launch_bounds__(256) void stats_kernel(
    const float* __restrict__ out, float* __restrict__ stats) {
  const int j  = blockIdx.x * 256 + threadIdx.x;  // 0..32767 = nl*128+f
  const int nl = j >> 7;
  const int f  = j & 127;
  const float* p = out + ((size_t)(CROP0 + nl)) * F + f;
  float s = 0.f, s2 = 0.f;
#pragma unroll 8
  for (int b = 0; b < BATCH; ++b) {
    float v = p[(size_t)b * NADJ * F];
    s += v;
    s2 += v * v;
  }
  const float mean = s * (1.f / BATCH);
  const float var  = s2 * (1.f / BATCH) - mean * mean;
  stats[j]             = mean;
  stats[32768 + j]     = rsqrtf(var + BN_EPS);
}

// ---------------------------------------------------------------------------
// K4: full output write. In-crop: normalize in place. Out-of-crop: beta.
// ---------------------------------------------------------------------------
__global__ __launch_bounds__(256) void finalize_kernel(
    float* __restrict__ out, const float* __restrict__ stats,
    const float* __restrict__ gamma, const float* __restrict__ beta) {
  const size_t i = ((size_t)blockIdx.x * 256 + threadIdx.x) * 4;
  const int nf = (int)(i & (size_t)(NADJ * F - 1));  // n*128+f
  const int n  = nf >> 7;
  float4 bt = *reinterpret_cast<const float4*>(&beta[nf]);
  float4 y;
  if (n >= CROP0 && n < CROP1) {
    const int jj = ((n - CROP0) << 7) | (nf & 127);
    float4 x  = *reinterpret_cast<const float4*>(&out[i]);
    float4 mn = *reinterpret_cast<const float4*>(&stats[jj]);
    float4 rs = *reinterpret_cast<const float4*>(&stats[32768 + jj]);
    float4 gm = *reinterpret_cast<const float4*>(&gamma[nf]);
    y.x = (x.x - mn.x) * rs.x * gm.x + bt.x;
    y.y = (x.y - mn.y) * rs.y * gm.y + bt.y;
    y.z = (x.z - mn.z) * rs.z * gm.z + bt.z;
    y.w = (x.w - mn.w) * rs.w * gm.w + bt.w;
  } else {
    y = bt;
  }
  *reinterpret_cast<float4*>(&out[i]) = y;
}

extern "C" void kernel_launch(void* const* d_in, const int* in_sizes, int n_in,
                              void* d_out, int out_size, void* d_ws,
                              size_t ws_size, hipStream_t stream) {
  const float* input = (const float*)d_in[0];
  const float* adj   = (const float*)d_in[1];
  const float* W     = (const float*)d_in[2];
  const float* gamma = (const float*)d_in[3];
  const float* beta  = (const float*)d_in[4];
  float* out = (float*)d_out;

  float* S     = (float*)d_ws;                       // 64*256*128 floats = 8 MB
  float* stats = (float*)d_ws + (size_t)BATCH * CN * F;  // 65536 floats

  dim3 g1(8, BATCH);
  support_kernel<<<g1, 256, 0, stream>>>(input, W, S);
  dim3 g2(8, BATCH);
  aggregate_kernel<<<g2, 256, 0, stream>>>(adj, S, out);
  stats_kernel<<<128, 256, 0, stream>>>(out, stats);
  // 64*512*128 / 4 / 256 = 4096 blocks
  finalize_kernel<<<4096, 256, 0, stream>>>(out, stats, gamma, beta);
}

// Round 2
// 41.708 us; speedup vs baseline: 1.4273x; 1.4273x over previous
//
#include <hip/hip_runtime.h>
#include <hip/hip_bf16.h>

#define BATCH 64
#define NADJ  512
#define F     128
#define CROP0 128
#define CROP1 384
#define CN    256
#define BN_EPS 1e-5f

typedef __attribute__((ext_vector_type(8))) short short8;
typedef __attribute__((ext_vector_type(4))) float f32x4;

__device__ __forceinline__ ushort f2bf(float x) {
  __hip_bfloat16 h = __float2bfloat16(x);  // RNE
  return *reinterpret_cast<ushort*>(&h);
}

// ---------------------------------------------------------------------------
// K1: St[b][f][m] = (input_crop @ W)^T in bf16.  MFMA 16x16x32 bf16.
// Block: 64 m-rows x 128 f, 4 waves (2x2). K = 128 staged fully in LDS.
// ---------------------------------------------------------------------------
__global__ __launch_bounds__(256) void support_mfma(
    const float* __restrict__ input, const float* __restrict__ W,
    ushort* __restrict__ St) {
  const int b  = blockIdx.y;
  const int m0 = blockIdx.x * 64;
  __shared__ ushort a_lds[64][136];    // input tile [m][i] bf16
  __shared__ ushort wt_lds[128][136];  // W^T [f][i] bf16
  const int tid = threadIdx.x;

  // stage input tile (64 x 128 fp32 -> bf16), coalesced float4 reads
  for (int idx = tid; idx < 64 * 32; idx += 256) {
    const int ml = idx >> 5, i0 = (idx & 31) * 4;
    const float4 v = *reinterpret_cast<const float4*>(
        &input[((size_t)b * NADJ + CROP0 + m0 + ml) * F + i0]);
    *reinterpret_cast<ushort4*>(&a_lds[ml][i0]) =
        make_ushort4(f2bf(v.x), f2bf(v.y), f2bf(v.z), f2bf(v.w));
  }
  // stage W transposed (lane -> f: coalesced reads; 8-way LDS write conflict,
  // one-time 32KB stage, acceptable)
  for (int idx = tid; idx < 128 * 128; idx += 256) {
    const int i = idx >> 7, f = idx & 127;
    wt_lds[f][i] = f2bf(W[idx]);
  }
  __syncthreads();

  const int l = tid & 63, w = tid >> 6;
  const int wm = (w >> 1) * 32;   // wave m-offset
  const int wf = (w & 1) * 64;    // wave f-offset
  const int lr = l & 15, lg = l >> 4;
  f32x4 acc[2][4] = {};

#pragma unroll
  for (int ks = 0; ks < 4; ++ks) {
    const int kb = ks * 32 + lg * 8;
    short8 av[2], bv[4];
#pragma unroll
    for (int mi = 0; mi < 2; ++mi)
      av[mi] = *reinterpret_cast<const short8*>(&a_lds[wm + mi * 16 + lr][kb]);
#pragma unroll
    for (int fi = 0; fi < 4; ++fi)
      bv[fi] = *reinterpret_cast<const short8*>(&wt_lds[wf + fi * 16 + lr][kb]);
#pragma unroll
    for (int mi = 0; mi < 2; ++mi)
#pragma unroll
      for (int fi = 0; fi < 4; ++fi)
        acc[mi][fi] = __builtin_amdgcn_mfma_f32_16x16x32_bf16(
            av[mi], bv[fi], acc[mi][fi], 0, 0, 0);
  }

  // D: col(f)=lane&15, row(m)=4*(lane>>4)+reg -> 4 consecutive m = 8B store
#pragma unroll
  for (int mi = 0; mi < 2; ++mi)
#pragma unroll
    for (int fi = 0; fi < 4; ++fi) {
      const int f = wf + fi * 16 + lr;
      const int m = m0 + wm + mi * 16 + lg * 4;
      *reinterpret_cast<ushort4*>(&St[((size_t)b * F + f) * CN + m]) =
          make_ushort4(f2bf(acc[mi][fi][0]), f2bf(acc[mi][fi][1]),
                       f2bf(acc[mi][fi][2]), f2bf(acc[mi][fi][3]));
    }
}

// ---------------------------------------------------------------------------
// K2: out_crop[b][n][f] = adj_crop[b][n][:] @ S[b][:][f].  MFMA bf16.
// Block: 64 n-rows x 128 f, 4 waves (2x2). K = 256 in chunks of 64.
// ---------------------------------------------------------------------------
__global__ __launch_bounds__(256) void aggregate_mfma(
    const float* __restrict__ adj, const ushort* __restrict__ St,
    float* __restrict__ out) {
  const int b  = blockIdx.y;
  const int n0 = blockIdx.x * 64;
  __shared__ ushort a_lds[64][72];   // adj tile [n][m] bf16
  __shared__ ushort b_lds[128][72];  // St tile [f][m] bf16
  const int tid = threadIdx.x;
  const int l = tid & 63, w = tid >> 6;
  const int wn = (w >> 1) * 32;
  const int wf = (w & 1) * 64;
  const int lr = l & 15, lg = l >> 4;
  f32x4 acc[2][4] = {};

  const float*  adjb = adj + ((size_t)b * NADJ + CROP0 + n0) * NADJ + CROP0;
  const ushort* Stb  = St + (size_t)b * F * CN;

  for (int mc = 0; mc < CN; mc += 64) {
    __syncthreads();
    // stage adj tile 64x64 fp32 -> bf16 (float4 reads, 8B LDS writes)
    for (int idx = tid; idx < 64 * 16; idx += 256) {
      const int nl = idx >> 4, c4 = (idx & 15) * 4;
      const float4 v = *reinterpret_cast<const float4*>(
          &adjb[(size_t)nl * NADJ + mc + c4]);
      *reinterpret_cast<ushort4*>(&a_lds[nl][c4]) =
          make_ushort4(f2bf(v.x), f2bf(v.y), f2bf(v.z), f2bf(v.w));
    }
    // stage St tile 128 x 64 bf16 (16B copies)
    for (int idx = tid; idx < 128 * 8; idx += 256) {
      const int f = idx >> 3, c8 = (idx & 7) * 8;
      *reinterpret_cast<uint4*>(&b_lds[f][c8]) =
          *reinterpret_cast<const uint4*>(&Stb[(size_t)f * CN + mc + c8]);
    }
    __syncthreads();
#pragma unroll
    for (int ks = 0; ks < 2; ++ks) {
      const int kb = ks * 32 + lg * 8;
      short8 av[2], bv[4];
#pragma unroll
      for (int mi = 0; mi < 2; ++mi)
        av[mi] =
            *reinterpret_cast<const short8*>(&a_lds[wn + mi * 16 + lr][kb]);
#pragma unroll
      for (int fi = 0; fi < 4; ++fi)
        bv[fi] =
            *reinterpret_cast<const short8*>(&b_lds[wf + fi * 16 + lr][kb]);
#pragma unroll
      for (int mi = 0; mi < 2; ++mi)
#pragma unroll
        for (int fi = 0; fi < 4; ++fi)
          acc[mi][fi] = __builtin_amdgcn_mfma_f32_16x16x32_bf16(
              av[mi], bv[fi], acc[mi][fi], 0, 0, 0);
    }
  }

  // epilogue: fp32 scalar stores into out crop rows
#pragma unroll
  for (int mi = 0; mi < 2; ++mi)
#pragma unroll
    for (int fi = 0; fi < 4; ++fi) {
      const int f = wf + fi * 16 + lr;
      const int n = n0 + wn + mi * 16 + lg * 4;
#pragma unroll
      for (int r = 0; r < 4; ++r)
        out[((size_t)b * NADJ + CROP0 + n + r) * F + f] = acc[mi][fi][r];
    }
}

// ---------------------------------------------------------------------------
// K3: per-(n,f) batch stats over B=64 on crop rows of out.
// ---------------------------------------------------------------------------
__global__ __launch_bounds__(256) void stats_kernel(
    const float* __restrict__ out, float* __restrict__ stats) {
  const int j  = blockIdx.x * 256 + threadIdx.x;  // nl*128+f
  const int nl = j >> 7;
  const int f  = j & 127;
  const float* p = out + ((size_t)(CROP0 + nl)) * F + f;
  float s = 0.f, s2 = 0.f;
#pragma unroll 8
  for (int b = 0; b < BATCH; ++b) {
    const float v = p[(size_t)b * NADJ * F];
    s += v;
    s2 += v * v;
  }
  const float mean = s * (1.f / BATCH);
  const float var  = s2 * (1.f / BATCH) - mean * mean;
  stats[j]         = mean;
  stats[32768 + j] = rsqrtf(var + BN_EPS);
}

// ---------------------------------------------------------------------------
// K4: full output write. In-crop: normalize in place. Out-of-crop: beta.
// ---------------------------------------------------------------------------
__global__ __launch_bounds__(256) void finalize_kernel(
    float* __restrict__ out, const float* __restrict__ stats,
    const float* __restrict__ gamma, const float* __restrict__ beta) {
  const size_t i = ((size_t)blockIdx.x * 256 + threadIdx.x) * 4;
  const int nf = (int)(i & (size_t)(NADJ * F - 1));
  const int n  = nf >> 7;
  const float4 bt = *reinterpret_cast<const float4*>(&beta[nf]);
  float4 y;
  if (n >= CROP0 && n < CROP1) {
    const int jj = ((n - CROP0) << 7) | (nf & 127);
    const float4 x  = *reinterpret_cast<const float4*>(&out[i]);
    const float4 mn = *reinterpret_cast<const float4*>(&stats[jj]);
    const float4 rs = *reinterpret_cast<const float4*>(&stats[32768 + jj]);
    const float4 gm = *reinterpret_cast<const float4*>(&gamma[nf]);
    y.x = (x.x - mn.x) * rs.x * gm.x + bt.x;
    y.y = (x.y - mn.y) * rs.y * gm.y + bt.y;
    y.z = (x.z - mn.z) * rs.z * gm.z + bt.z;
    y.w = (x.w - mn.w) * rs.w * gm.w + bt.w;
  } else {
    y = bt;
  }
  *reinterpret_cast<float4*>(&out[i]) = y;
}

extern "C" void kernel_launch(void* const* d_in, const int* in_sizes, int n_in,
                              void* d_out, int out_size, void* d_ws,
                              size_t ws_size, hipStream_t stream) {
  const float* input = (const float*)d_in[0];
  const float* adj   = (const float*)d_in[1];
  const float* W     = (const float*)d_in[2];
  const float* gamma = (const float*)d_in[3];
  const float* beta  = (const float*)d_in[4];
  float* out = (float*)d_out;

  ushort* St    = (ushort*)d_ws;  // 64*128*256 bf16 = 4 MB
  float*  stats = (float*)((char*)d_ws + 4u * 1024u * 1024u);  // 256 KB

  dim3 g1(4, BATCH);
  support_mfma<<<g1, 256, 0, stream>>>(input, W, St);
  dim3 g2(4, BATCH);
  aggregate_mfma<<<g2, 256, 0, stream>>>(adj, St, out);
  stats_kernel<<<128, 256, 0, stream>>>(out, stats);
  finalize_kernel<<<4096, 256, 0, stream>>>(out, stats, gamma, beta);
}

// Round 3
// 40.281 us; speedup vs baseline: 1.4779x; 1.0354x over previous
//
#include <hip/hip_runtime.h>
#include <hip/hip_bf16.h>

#define BATCH 64
#define NADJ  512
#define F     128
#define CROP0 128
#define CROP1 384
#define CN    256
#define BN_EPS 1e-5f

typedef __attribute__((ext_vector_type(8))) short short8;
typedef __attribute__((ext_vector_type(4))) float f32x4;

__device__ __forceinline__ ushort f2bf(float x) {
  __hip_bfloat16 h = __float2bfloat16(x);  // RNE
  return *reinterpret_cast<ushort*>(&h);
}

// ---------------------------------------------------------------------------
// Fused K1+K2: per block (batch b, 64 crop n-rows):
//   for each m-chunk of 64:
//     S_chunk[m][f] = input[b][crop m][:] @ W          (MFMA, -> LDS bf16 [f][m])
//     acc[n][f]    += adj[b][crop n][crop m-chunk] @ S_chunk   (MFMA)
// Eliminates the St global round-trip entirely.
// LDS: wt 34.8K + a_in 17.4K + st 18.4K + adjt 9.2K = 79.9 KB
// ---------------------------------------------------------------------------
__global__ __launch_bounds__(256) void gcn_fused(
    const float* __restrict__ input, const float* __restrict__ adj,
    const float* __restrict__ W, float* __restrict__ out) {
  const int b  = blockIdx.y;
  const int n0 = blockIdx.x * 64;  // within crop
  __shared__ ushort wt[128][136];   // W^T [f][i]
  __shared__ ushort a_in[64][136];  // input chunk [ml][i]
  __shared__ ushort st[128][72];    // S^T chunk [f][ml]
  __shared__ ushort adjt[64][72];   // adj chunk [nl][ml]
  const int tid = threadIdx.x;
  const int l = tid & 63, w = tid >> 6;
  const int lr = l & 15, lg = l >> 4;
  const int wn = (w >> 1) * 32, wf = (w & 1) * 64;

  // stage W^T once per block (coalesced f-major reads, scalar LDS writes)
  for (int idx = tid; idx < 128 * 128; idx += 256) {
    const int i = idx >> 7, f = idx & 127;
    wt[f][i] = f2bf(W[idx]);
  }

  const float* adjb = adj + ((size_t)b * NADJ + CROP0 + n0) * NADJ + CROP0;
  const float* inb  = input + ((size_t)b * NADJ + CROP0) * F;

  f32x4 acc2[2][4] = {};

  for (int mc = 0; mc < CN; mc += 64) {
    __syncthreads();  // prev chunk's MFMA reads done before restage
    // stage input chunk 64x128 fp32 -> bf16
    for (int idx = tid; idx < 64 * 32; idx += 256) {
      const int ml = idx >> 5, i0 = (idx & 31) * 4;
      const float4 v = *reinterpret_cast<const float4*>(
          &inb[(size_t)(mc + ml) * F + i0]);
      *reinterpret_cast<ushort4*>(&a_in[ml][i0]) =
          make_ushort4(f2bf(v.x), f2bf(v.y), f2bf(v.z), f2bf(v.w));
    }
    // stage adj chunk 64x64 fp32 -> bf16
    for (int idx = tid; idx < 64 * 16; idx += 256) {
      const int nl = idx >> 4, c4 = (idx & 15) * 4;
      const float4 v = *reinterpret_cast<const float4*>(
          &adjb[(size_t)nl * NADJ + mc + c4]);
      *reinterpret_cast<ushort4*>(&adjt[nl][c4]) =
          make_ushort4(f2bf(v.x), f2bf(v.y), f2bf(v.z), f2bf(v.w));
    }
    __syncthreads();

    // S-compute: wave w owns m-rows [w*16, w*16+16) of this chunk, all 128 f
    f32x4 sacc[8] = {{0.f, 0.f, 0.f, 0.f}, {0.f, 0.f, 0.f, 0.f},
                     {0.f, 0.f, 0.f, 0.f}, {0.f, 0.f, 0.f, 0.f},
                     {0.f, 0.f, 0.f, 0.f}, {0.f, 0.f, 0.f, 0.f},
                     {0.f, 0.f, 0.f, 0.f}, {0.f, 0.f, 0.f, 0.f}};
#pragma unroll
    for (int ks = 0; ks < 4; ++ks) {
      const int kb = ks * 32 + lg * 8;
      const short8 av = *reinterpret_cast<const short8*>(&a_in[w * 16 + lr][kb]);
#pragma unroll
      for (int fi = 0; fi < 8; ++fi) {
        const short8 bv = *reinterpret_cast<const short8*>(&wt[fi * 16 + lr][kb]);
        sacc[fi] =
            __builtin_amdgcn_mfma_f32_16x16x32_bf16(av, bv, sacc[fi], 0, 0, 0);
      }
    }
    // D layout: col(f)=lane&15, row(m)=4*(lane>>4)+reg -> write S^T [f][m]
#pragma unroll
    for (int fi = 0; fi < 8; ++fi)
      *reinterpret_cast<ushort4*>(&st[fi * 16 + lr][w * 16 + lg * 4]) =
          make_ushort4(f2bf(sacc[fi][0]), f2bf(sacc[fi][1]),
                       f2bf(sacc[fi][2]), f2bf(sacc[fi][3]));
    __syncthreads();  // st visible

    // aggregate MFMA over this chunk: K = 64
#pragma unroll
    for (int ks = 0; ks < 2; ++ks) {
      const int kb = ks * 32 + lg * 8;
      short8 av[2], bv[4];
#pragma unroll
      for (int mi = 0; mi < 2; ++mi)
        av[mi] = *reinterpret_cast<const short8*>(&adjt[wn + mi * 16 + lr][kb]);
#pragma unroll
      for (int fi = 0; fi < 4; ++fi)
        bv[fi] = *reinterpret_cast<const short8*>(&st[wf + fi * 16 + lr][kb]);
#pragma unroll
      for (int mi = 0; mi < 2; ++mi)
#pragma unroll
        for (int fi = 0; fi < 4; ++fi)
          acc2[mi][fi] = __builtin_amdgcn_mfma_f32_16x16x32_bf16(
              av[mi], bv[fi], acc2[mi][fi], 0, 0, 0);
    }
  }

  // epilogue: fp32 stores into out crop rows (64B-coalesced per 16 lanes)
#pragma unroll
  for (int mi = 0; mi < 2; ++mi)
#pragma unroll
    for (int fi = 0; fi < 4; ++fi) {
      const int f = wf + fi * 16 + lr;
      const int n = n0 + wn + mi * 16 + lg * 4;
#pragma unroll
      for (int r = 0; r < 4; ++r)
        out[((size_t)b * NADJ + CROP0 + n + r) * F + f] = acc2[mi][fi][r];
    }
}

// ---------------------------------------------------------------------------
// Stats: per-(n,f) batch mean / rsqrt(var) over B=64. 512 blocks,
// 4 batch-groups x 16 loads per thread + LDS reduce.
// ---------------------------------------------------------------------------
__global__ __launch_bounds__(256) void stats_kernel(
    const float* __restrict__ out, float* __restrict__ stats) {
  __shared__ float s_l[256], s2_l[256];
  const int jl = threadIdx.x & 63, bg = threadIdx.x >> 6;
  const int j  = blockIdx.x * 64 + jl;  // nl*128+f
  const int nl = j >> 7, f = j & 127;
  const float* p = out + ((size_t)(CROP0 + nl)) * F + f +
                   (size_t)bg * 16 * NADJ * F;
  float s = 0.f, s2 = 0.f;
#pragma unroll 4
  for (int bb = 0; bb < 16; ++bb) {
    const float v = p[(size_t)bb * NADJ * F];
    s += v;
    s2 += v * v;
  }
  s_l[threadIdx.x]  = s;
  s2_l[threadIdx.x] = s2;
  __syncthreads();
  if (threadIdx.x < 64) {
    s  = s_l[jl] + s_l[64 + jl] + s_l[128 + jl] + s_l[192 + jl];
    s2 = s2_l[jl] + s2_l[64 + jl] + s2_l[128 + jl] + s2_l[192 + jl];
    const float mean = s * (1.f / BATCH);
    const float var  = s2 * (1.f / BATCH) - mean * mean;
    stats[j]         = mean;
    stats[32768 + j] = rsqrtf(var + BN_EPS);
  }
}

// ---------------------------------------------------------------------------
// Finalize: full output write. In-crop: normalize in place. Else: beta.
// ---------------------------------------------------------------------------
__global__ __launch_bounds__(256) void finalize_kernel(
    float* __restrict__ out, const float* __restrict__ stats,
    const float* __restrict__ gamma, const float* __restrict__ beta) {
  const size_t i = ((size_t)blockIdx.x * 256 + threadIdx.x) * 4;
  const int nf = (int)(i & (size_t)(NADJ * F - 1));
  const int n  = nf >> 7;
  const float4 bt = *reinterpret_cast<const float4*>(&beta[nf]);
  float4 y;
  if (n >= CROP0 && n < CROP1) {
    const int jj = ((n - CROP0) << 7) | (nf & 127);
    const float4 x  = *reinterpret_cast<const float4*>(&out[i]);
    const float4 mn = *reinterpret_cast<const float4*>(&stats[jj]);
    const float4 rs = *reinterpret_cast<const float4*>(&stats[32768 + jj]);
    const float4 gm = *reinterpret_cast<const float4*>(&gamma[nf]);
    y.x = (x.x - mn.x) * rs.x * gm.x + bt.x;
    y.y = (x.y - mn.y) * rs.y * gm.y + bt.y;
    y.z = (x.z - mn.z) * rs.z * gm.z + bt.z;
    y.w = (x.w - mn.w) * rs.w * gm.w + bt.w;
  } else {
    y = bt;
  }
  *reinterpret_cast<float4*>(&out[i]) = y;
}

extern "C" void kernel_launch(void* const* d_in, const int* in_sizes, int n_in,
                              void* d_out, int out_size, void* d_ws,
                              size_t ws_size, hipStream_t stream) {
  const float* input = (const float*)d_in[0];
  const float* adj   = (const float*)d_in[1];
  const float* W     = (const float*)d_in[2];
  const float* gamma = (const float*)d_in[3];
  const float* beta  = (const float*)d_in[4];
  float* out = (float*)d_out;

  float* stats = (float*)d_ws;  // 65536 floats

  dim3 g1(4, BATCH);
  gcn_fused<<<g1, 256, 0, stream>>>(input, adj, W, out);
  stats_kernel<<<512, 256, 0, stream>>>(out, stats);
  finalize_kernel<<<4096, 256, 0, stream>>>(out, stats, gamma, beta);
}